// Round 4
// baseline (618.346 us; speedup 1.0000x reference)
//
#include <hip/hip_runtime.h>
#include <math.h>

#define DD 128
#define CC 40

typedef __bf16 bf16x8 __attribute__((ext_vector_type(8)));
typedef float f32x4 __attribute__((ext_vector_type(4)));

union BF8 { uint4 q; bf16x8 v; ushort us[8]; };

static __device__ __forceinline__ ushort f2bf(float x) {
    union { float f; unsigned u; } v; v.f = x;
    unsigned r = (v.u + 0x7FFFu + ((v.u >> 16) & 1u)) >> 16;   // RNE
    return (ushort)r;
}
static __device__ __forceinline__ float bf2f(ushort u) {
    union { unsigned u; float f; } v; v.u = ((unsigned)u) << 16;
    return v.f;
}
// per-16-bit unsigned max == bf16 max for non-negative values (post-ReLU)
static __device__ __forceinline__ uint4 bfmax4(uint4 a, uint4 b) {
    union U { uint4 q; ushort us[8]; } x, y;
    x.q = a; y.q = b;
#pragma unroll
    for (int i = 0; i < 8; ++i) x.us[i] = (x.us[i] > y.us[i]) ? x.us[i] : y.us[i];
    return x.q;
}

// ---------------------------------------------------------------------------
// Detect edge_index storage: int32 vs int64 (odd 32-bit words all zero).
__global__ void detect_kernel(const unsigned* __restrict__ e, int* __restrict__ flag) {
    int t = threadIdx.x;
    unsigned nz = 0;
    for (int j = 0; j < 16; ++j) nz |= e[2 * (t * 16 + j) + 1];
    unsigned long long b = __ballot(nz != 0);
    if (t == 0) *flag = (b != 0) ? 1 : 0;
}

__device__ __forceinline__ int edge_at(const void* eptr, int is32, long long idx) {
    if (is32) return ((const int*)eptr)[idx];
    return (int)((const long long*)eptr)[idx];
}

__global__ void hist_kernel(const void* __restrict__ eptr, int* __restrict__ cnt,
                            const int* __restrict__ flag, int E) {
    int e = blockIdx.x * blockDim.x + threadIdx.x;
    if (e >= E) return;
    int is32 = *flag;
    int r = edge_at(eptr, is32, e);
    atomicAdd(&cnt[r], 1);
}

// Hierarchical exclusive scan (1024/block): local scan + block sums.
__global__ __launch_bounds__(1024) void scanA_kernel(int* __restrict__ cnt,
                                                     int* __restrict__ row_ptr,
                                                     float* __restrict__ dinv,
                                                     int* __restrict__ blksum, int N) {
    __shared__ int swave[16];
    int tid = threadIdx.x;
    int lane = tid & 63, wid = tid >> 6;
    int i = blockIdx.x * 1024 + tid;
    int v = (i < N) ? cnt[i] : 0;
    int incl = v;
#pragma unroll
    for (int off = 1; off < 64; off <<= 1) {
        int t = __shfl_up(incl, off);
        if (lane >= off) incl += t;
    }
    if (lane == 63) swave[wid] = incl;
    __syncthreads();
    if (tid < 16) {
        int t = swave[tid];
#pragma unroll
        for (int off = 1; off < 16; off <<= 1) {
            int u = __shfl_up(t, off);
            if (tid >= off) t += u;
        }
        swave[tid] = t;
    }
    __syncthreads();
    int waveoff = (wid == 0) ? 0 : swave[wid - 1];
    if (i < N) {
        row_ptr[i] = waveoff + incl - v;
        dinv[i] = rsqrtf((float)v + 1.0f);
        cnt[i] = 0;
    }
    if (tid == 0) blksum[blockIdx.x] = swave[15];
}

__global__ __launch_bounds__(128) void scanB_kernel(int* __restrict__ blksum, int nb) {
    __shared__ int s[128];
    int t = threadIdx.x;
    int orig = (t < nb) ? blksum[t] : 0;
    s[t] = orig;
    __syncthreads();
    for (int off = 1; off < 128; off <<= 1) {
        int v = (t >= off) ? s[t - off] : 0;
        __syncthreads();
        s[t] += v;
        __syncthreads();
    }
    if (t < nb) blksum[t] = s[t] - orig;
}

__global__ void scanC_kernel(int* __restrict__ row_ptr, const int* __restrict__ blksum,
                             int N, int E) {
    int i = blockIdx.x * blockDim.x + threadIdx.x;
    if (i < N) row_ptr[i] += blksum[i >> 10];
    if (i == 0) row_ptr[N] = E;
}

__global__ void scatter_kernel(const void* __restrict__ eptr, const int* __restrict__ row_ptr,
                               int* __restrict__ cursor, int* __restrict__ csr,
                               const int* __restrict__ flag, int E) {
    int e = blockIdx.x * blockDim.x + threadIdx.x;
    if (e >= E) return;
    int is32 = *flag;
    int r = edge_at(eptr, is32, e);
    int c = edge_at(eptr, is32, (long long)E + e);
    int pos = row_ptr[r] + atomicAdd(&cursor[r], 1);
    csr[pos] = c;
}

// ---------------------------------------------------------------------------
// fp32 -> bf16 conversions
__global__ void cvtx_kernel(const float* __restrict__ x, ushort* __restrict__ xb, long n4) {
    long i = (long)blockIdx.x * blockDim.x + threadIdx.x;
    if (i >= n4) return;
    float4 v = *(const float4*)&x[i * 4];
    ushort4 o;
    o.x = f2bf(v.x); o.y = f2bf(v.y); o.z = f2bf(v.z); o.w = f2bf(v.w);
    *(ushort4*)&xb[i * 4] = o;
}

// Wt[l][col][k] = W[l][k][col] (bf16, K-major for MFMA B frags)
__global__ void cvtw_kernel(const float* __restrict__ W, ushort* __restrict__ Wt, int total) {
    int idx = blockIdx.x * 256 + threadIdx.x;
    if (idx >= total) return;
    int l = idx >> 14, rem = idx & 16383, k = rem >> 7, col = rem & 127;
    Wt[(l << 14) + col * DD + k] = f2bf(W[idx]);
}

// Wp[col][k] = lin_w[k][col], zero-padded to 48 cols (bf16, K-major)
__global__ void cvtlw_kernel(const float* __restrict__ lw, ushort* __restrict__ Wp) {
    int idx = blockIdx.x * 256 + threadIdx.x;
    if (idx >= 48 * DD) return;
    int col = idx >> 7, k = idx & 127;
    Wp[col * DD + k] = (col < CC) ? f2bf(lw[k * CC + col]) : (ushort)0;
}

// ---------------------------------------------------------------------------
// Y[N,128](bf16) = X[N,128](bf16) @ W via Wt[col][k].
// Block 256 = 4 waves; wave owns 16 rows x 128 cols = 8 MFMA 16x16x32 tiles.
__global__ __launch_bounds__(256) void mm_kernel(const ushort* __restrict__ Xb,
                                                 const ushort* __restrict__ Wt,
                                                 ushort* __restrict__ Y, int N) {
    int wave = threadIdx.x >> 6, lane = threadIdx.x & 63;
    int row0 = blockIdx.x * 64 + wave * 16;
    int lrow = lane & 15, kgrp = lane >> 4;
    const ushort* arow = &Xb[(size_t)(row0 + lrow) * DD + kgrp * 8];
    f32x4 acc[8];
#pragma unroll
    for (int j = 0; j < 8; ++j) acc[j] = (f32x4){0.f, 0.f, 0.f, 0.f};
#pragma unroll
    for (int kc = 0; kc < 4; ++kc) {
        BF8 a;
        a.q = *(const uint4*)&arow[kc * 32];
#pragma unroll
        for (int j = 0; j < 8; ++j) {
            BF8 b;
            b.q = *(const uint4*)&Wt[(size_t)(j * 16 + lrow) * DD + kc * 32 + kgrp * 8];
            acc[j] = __builtin_amdgcn_mfma_f32_16x16x32_bf16(a.v, b.v, acc[j], 0, 0, 0);
        }
    }
#pragma unroll
    for (int j = 0; j < 8; ++j) {
        int col = j * 16 + lrow;
#pragma unroll
        for (int r = 0; r < 4; ++r) {
            int row = row0 + kgrp * 4 + r;
            if (row < N) Y[(size_t)row * DD + col] = f2bf(acc[j][r]);
        }
    }
}

// ---------------------------------------------------------------------------
// Fused CSR gather-agg + self loop + bias + BN + ReLU; bf16 in/out, fp32 accum.
// One 64-lane wave per node: 4 edge-slots x 16 channel-lanes (8 ch each).
__global__ __launch_bounds__(256) void agg_kernel(
    const ushort* __restrict__ h1b, const int* __restrict__ row_ptr,
    const int* __restrict__ csr, const float* __restrict__ dinv,
    const float* __restrict__ bias, const float* __restrict__ gamma,
    const float* __restrict__ beta, const float* __restrict__ mean,
    const float* __restrict__ var, ushort* __restrict__ hout, int N) {
    int node = (blockIdx.x * blockDim.x + threadIdx.x) >> 6;
    if (node >= N) return;
    int lane = threadIdx.x & 63;
    int cl = lane & 15, es = lane >> 4;
    int c = cl * 8;

    float acc[8];
#pragma unroll
    for (int i = 0; i < 8; ++i) acc[i] = 0.f;

    int s = row_ptr[node], e = row_ptr[node + 1];
    for (int p = s + es; p < e; p += 4) {
        int src = csr[p];                 // broadcast across the 16 ch-lanes
        float w = dinv[src];
        BF8 hv;
        hv.q = *(const uint4*)&h1b[(size_t)src * DD + c];
#pragma unroll
        for (int i = 0; i < 8; ++i) acc[i] = fmaf(w, bf2f(hv.us[i]), acc[i]);
    }
    // reduce across the 4 edge slots
#pragma unroll
    for (int i = 0; i < 8; ++i) {
        acc[i] += __shfl_xor(acc[i], 16, 64);
        acc[i] += __shfl_xor(acc[i], 32, 64);
    }
    if (es == 0) {
        float di = dinv[node];
        float sn = di * di;
        BF8 sv;
        sv.q = *(const uint4*)&h1b[(size_t)node * DD + c];
        float bb[8], gg[8], be[8], mm[8], vv[8];
        *(float4*)&bb[0] = *(const float4*)&bias[c];  *(float4*)&bb[4] = *(const float4*)&bias[c + 4];
        *(float4*)&gg[0] = *(const float4*)&gamma[c]; *(float4*)&gg[4] = *(const float4*)&gamma[c + 4];
        *(float4*)&be[0] = *(const float4*)&beta[c];  *(float4*)&be[4] = *(const float4*)&beta[c + 4];
        *(float4*)&mm[0] = *(const float4*)&mean[c];  *(float4*)&mm[4] = *(const float4*)&mean[c + 4];
        *(float4*)&vv[0] = *(const float4*)&var[c];   *(float4*)&vv[4] = *(const float4*)&var[c + 4];
        BF8 o;
#pragma unroll
        for (int i = 0; i < 8; ++i) {
            float h = fmaf(di, acc[i], fmaf(sn, bf2f(sv.us[i]), bb[i]));
            float y = fmaxf(gg[i] * (h - mm[i]) * rsqrtf(vv[i] + 1e-5f) + be[i], 0.f);
            o.us[i] = f2bf(y);
        }
        *(uint4*)&hout[(size_t)node * DD + c] = o.q;
    }
}

// ---------------------------------------------------------------------------
// out = log_softmax( (max_l h_l) @ lin_w + lin_b ). MFMA, zero LDS.
// Wave = 16 nodes; JK-max fused into A-frag loads (integer max, post-ReLU>=0).
// B = Wp[48][128] K-major (12 KB, cache-resident), held in registers.
__global__ __launch_bounds__(256) void final_kernel(const ushort* __restrict__ hall,
                                                    size_t hstride, int L,
                                                    const ushort* __restrict__ Wp,
                                                    const float* __restrict__ lb,
                                                    float* __restrict__ out, int N) {
    int wave = threadIdx.x >> 6, lane = threadIdx.x & 63;
    int row0 = blockIdx.x * 64 + wave * 16;
    int lrow = lane & 15, kgrp = lane >> 4;
    int arow = row0 + lrow;
    bool rv = arow < N;
    const ushort* abase = &hall[(size_t)arow * DD + kgrp * 8];

    BF8 b[3][4];
#pragma unroll
    for (int j = 0; j < 3; ++j)
#pragma unroll
        for (int kc = 0; kc < 4; ++kc)
            b[j][kc].q = *(const uint4*)&Wp[(size_t)(j * 16 + lrow) * DD + kc * 32 + kgrp * 8];

    f32x4 acc[3];
#pragma unroll
    for (int j = 0; j < 3; ++j) acc[j] = (f32x4){0.f, 0.f, 0.f, 0.f};

#pragma unroll
    for (int kc = 0; kc < 4; ++kc) {
        uint4 m = make_uint4(0, 0, 0, 0);
        if (rv) {
            m = *(const uint4*)&abase[kc * 32];
            for (int l = 1; l < L; ++l)
                m = bfmax4(m, *(const uint4*)&abase[(size_t)l * hstride + kc * 32]);
        }
        BF8 a; a.q = m;
#pragma unroll
        for (int j = 0; j < 3; ++j)
            acc[j] = __builtin_amdgcn_mfma_f32_16x16x32_bf16(a.v, b[j][kc].v, acc[j], 0, 0, 0);
    }

    // lane holds cols j*16+lrow (valid < 40) for nodes row0 + kgrp*4 + r
    float lbv[3];
#pragma unroll
    for (int j = 0; j < 3; ++j) {
        int col = j * 16 + lrow;
        lbv[j] = (col < CC) ? lb[col] : 0.f;
    }
#pragma unroll
    for (int r = 0; r < 4; ++r) {
        int node = row0 + kgrp * 4 + r;
        float lg[3];
        float m = -1e30f;
#pragma unroll
        for (int j = 0; j < 3; ++j) {
            int col = j * 16 + lrow;
            float v = (col < CC) ? (acc[j][r] + lbv[j]) : -1e30f;
            lg[j] = v;
            m = fmaxf(m, v);
        }
        m = fmaxf(m, __shfl_xor(m, 1));
        m = fmaxf(m, __shfl_xor(m, 2));
        m = fmaxf(m, __shfl_xor(m, 4));
        m = fmaxf(m, __shfl_xor(m, 8));
        float s = 0.f;
#pragma unroll
        for (int j = 0; j < 3; ++j) {
            int col = j * 16 + lrow;
            if (col < CC) s += expf(lg[j] - m);
        }
        s += __shfl_xor(s, 1);
        s += __shfl_xor(s, 2);
        s += __shfl_xor(s, 4);
        s += __shfl_xor(s, 8);
        float lgs = logf(s);
        if (node < N) {
#pragma unroll
            for (int j = 0; j < 3; ++j) {
                int col = j * 16 + lrow;
                if (col < CC) out[(size_t)node * CC + col] = lg[j] - m - lgs;
            }
        }
    }
}

// ---------------------------------------------------------------------------
extern "C" void kernel_launch(void* const* d_in, const int* in_sizes, int n_in,
                              void* d_out, int out_size, void* d_ws, size_t ws_size,
                              hipStream_t stream) {
    const float* x      = (const float*)d_in[0];
    const void*  eidx   = d_in[1];
    const float* conv_w = (const float*)d_in[2];
    const float* conv_b = (const float*)d_in[3];
    const float* gamma  = (const float*)d_in[4];
    const float* beta   = (const float*)d_in[5];
    const float* mean   = (const float*)d_in[6];
    const float* var    = (const float*)d_in[7];
    const float* lin_w  = (const float*)d_in[8];
    const float* lin_b  = (const float*)d_in[9];
    float* out = (float*)d_out;

    const int N = in_sizes[0] / DD;          // 100000
    const int E = in_sizes[1] / 2;           // 800000
    const int L = in_sizes[3] / DD;          // 5
    const int NPAD = (N + 63) & ~63;         // 100032
    const size_t hstride = (size_t)NPAD * DD;
    const int NB = (N + 1023) / 1024;

    char* p = (char*)d_ws;
    auto alloc = [&](size_t bytes) -> char* {
        char* r = p;
        p += (bytes + 255) & ~(size_t)255;
        return r;
    };
    ushort* xb     = (ushort*)alloc(hstride * 2);            // matmul out / layer0 in
    ushort* hall   = (ushort*)alloc((size_t)L * hstride * 2);
    ushort* Wt     = (ushort*)alloc((size_t)L * DD * DD * 2);
    ushort* Wp     = (ushort*)alloc((size_t)48 * DD * 2);
    float*  dinv   = (float*)alloc((size_t)N * 4);
    int*    row_ptr= (int*)alloc((size_t)(N + 1) * 4);
    int*    cnt    = (int*)alloc((size_t)N * 4);
    int*    csr    = (int*)alloc((size_t)E * 4);
    int*    blksum = (int*)alloc(128 * 4);
    int*    flag   = (int*)alloc(4);

    detect_kernel<<<1, 64, 0, stream>>>((const unsigned*)eidx, flag);
    hipMemsetAsync(cnt, 0, (size_t)N * 4, stream);
    hist_kernel<<<(E + 255) / 256, 256, 0, stream>>>(eidx, cnt, flag, E);
    scanA_kernel<<<NB, 1024, 0, stream>>>(cnt, row_ptr, dinv, blksum, N);
    scanB_kernel<<<1, 128, 0, stream>>>(blksum, NB);
    scanC_kernel<<<(N + 255) / 256, 256, 0, stream>>>(row_ptr, blksum, N, E);
    scatter_kernel<<<(E + 255) / 256, 256, 0, stream>>>(eidx, row_ptr, cnt, csr, flag, E);

    cvtx_kernel<<<(int)(((size_t)N * DD / 4 + 255) / 256), 256, 0, stream>>>(x, xb, (long)N * DD / 4);
    cvtw_kernel<<<(L * DD * DD + 255) / 256, 256, 0, stream>>>(conv_w, Wt, L * DD * DD);
    cvtlw_kernel<<<(48 * DD + 255) / 256, 256, 0, stream>>>(lin_w, Wp);

    const ushort* X = xb;
    for (int l = 0; l < L; ++l) {
        // mm writes xb; layer 0 in-place is safe (block reads only its own rows first)
        mm_kernel<<<NPAD / 64, 256, 0, stream>>>(X, Wt + (size_t)l * DD * DD, xb, N);
        ushort* hl = hall + (size_t)l * hstride;
        agg_kernel<<<(int)(((size_t)N * 64 + 255) / 256), 256, 0, stream>>>(
            xb, row_ptr, csr, dinv,
            conv_b + (size_t)l * DD, gamma + (size_t)l * DD, beta + (size_t)l * DD,
            mean + (size_t)l * DD, var + (size_t)l * DD, hl, N);
        X = hl;
    }
    final_kernel<<<(N + 63) / 64, 256, 0, stream>>>(hall, hstride, L, Wp, lin_b, out, N);
}

// Round 5
// 435.498 us; speedup vs baseline: 1.4199x; 1.4199x over previous
//
#include <hip/hip_runtime.h>
#include <math.h>

#define DD 128
#define CC 40

typedef __bf16 bf16x8 __attribute__((ext_vector_type(8)));
typedef float f32x4 __attribute__((ext_vector_type(4)));

union BF8 { uint4 q; bf16x8 v; ushort us[8]; };

static __device__ __forceinline__ ushort f2bf(float x) {
    union { float f; unsigned u; } v; v.f = x;
    unsigned r = (v.u + 0x7FFFu + ((v.u >> 16) & 1u)) >> 16;   // RNE
    return (ushort)r;
}
static __device__ __forceinline__ float bf2f(ushort u) {
    union { unsigned u; float f; } v; v.u = ((unsigned)u) << 16;
    return v.f;
}
// per-16-bit unsigned max == bf16 max for non-negative values (post-ReLU)
static __device__ __forceinline__ uint4 bfmax4(uint4 a, uint4 b) {
    union U { uint4 q; ushort us[8]; } x, y;
    x.q = a; y.q = b;
#pragma unroll
    for (int i = 0; i < 8; ++i) x.us[i] = (x.us[i] > y.us[i]) ? x.us[i] : y.us[i];
    return x.q;
}

// ---------------------------------------------------------------------------
// Detect edge_index storage: int32 vs int64 (odd 32-bit words all zero).
__global__ void detect_kernel(const unsigned* __restrict__ e, int* __restrict__ flag) {
    int t = threadIdx.x;
    unsigned nz = 0;
    for (int j = 0; j < 16; ++j) nz |= e[2 * (t * 16 + j) + 1];
    unsigned long long b = __ballot(nz != 0);
    if (t == 0) *flag = (b != 0) ? 1 : 0;
}

__device__ __forceinline__ int edge_at(const void* eptr, int is32, long long idx) {
    if (is32) return ((const int*)eptr)[idx];
    return (int)((const long long*)eptr)[idx];
}

__global__ void hist_kernel(const void* __restrict__ eptr, int* __restrict__ cnt,
                            const int* __restrict__ flag, int E) {
    int e = blockIdx.x * blockDim.x + threadIdx.x;
    if (e >= E) return;
    int is32 = *flag;
    int r = edge_at(eptr, is32, e);
    atomicAdd(&cnt[r], 1);
}

// Hierarchical exclusive scan (1024/block): local scan + block sums.
__global__ __launch_bounds__(1024) void scanA_kernel(int* __restrict__ cnt,
                                                     int* __restrict__ row_ptr,
                                                     float* __restrict__ dinv,
                                                     int* __restrict__ blksum, int N) {
    __shared__ int swave[16];
    int tid = threadIdx.x;
    int lane = tid & 63, wid = tid >> 6;
    int i = blockIdx.x * 1024 + tid;
    int v = (i < N) ? cnt[i] : 0;
    int incl = v;
#pragma unroll
    for (int off = 1; off < 64; off <<= 1) {
        int t = __shfl_up(incl, off);
        if (lane >= off) incl += t;
    }
    if (lane == 63) swave[wid] = incl;
    __syncthreads();
    if (tid < 16) {
        int t = swave[tid];
#pragma unroll
        for (int off = 1; off < 16; off <<= 1) {
            int u = __shfl_up(t, off);
            if (tid >= off) t += u;
        }
        swave[tid] = t;
    }
    __syncthreads();
    int waveoff = (wid == 0) ? 0 : swave[wid - 1];
    if (i < N) {
        row_ptr[i] = waveoff + incl - v;
        dinv[i] = rsqrtf((float)v + 1.0f);
        cnt[i] = 0;
    }
    if (tid == 0) blksum[blockIdx.x] = swave[15];
}

__global__ __launch_bounds__(128) void scanB_kernel(int* __restrict__ blksum, int nb) {
    __shared__ int s[128];
    int t = threadIdx.x;
    int orig = (t < nb) ? blksum[t] : 0;
    s[t] = orig;
    __syncthreads();
    for (int off = 1; off < 128; off <<= 1) {
        int v = (t >= off) ? s[t - off] : 0;
        __syncthreads();
        s[t] += v;
        __syncthreads();
    }
    if (t < nb) blksum[t] = s[t] - orig;
}

__global__ void scanC_kernel(int* __restrict__ row_ptr, const int* __restrict__ blksum,
                             int N, int E) {
    int i = blockIdx.x * blockDim.x + threadIdx.x;
    if (i < N) row_ptr[i] += blksum[i >> 10];
    if (i == 0) row_ptr[N] = E;
}

__global__ void scatter_kernel(const void* __restrict__ eptr, const int* __restrict__ row_ptr,
                               int* __restrict__ cursor, int* __restrict__ csr,
                               const int* __restrict__ flag, int E) {
    int e = blockIdx.x * blockDim.x + threadIdx.x;
    if (e >= E) return;
    int is32 = *flag;
    int r = edge_at(eptr, is32, e);
    int c = edge_at(eptr, is32, (long long)E + e);
    int pos = row_ptr[r] + atomicAdd(&cursor[r], 1);
    csr[pos] = c;
}

// ---------------------------------------------------------------------------
// Wf: MFMA-fragment-ordered conv weights. For layer l, frag (kc,j), lane:
//   Wf[l][((kc*8+j)*64 + lane)*8 + i] = W[l][k][col],
//   k = kc*32 + (lane>>4)*8 + i, col = j*16 + (lane&15).
// A wave's B-frag load is then base + lane*16B -> one coalesced 1KB request.
__global__ void cvtw_kernel(const float* __restrict__ W, ushort* __restrict__ Wf, int total) {
    int tid = blockIdx.x * 256 + threadIdx.x;
    if (tid >= total) return;                      // total = L * 2048
    int l = tid >> 11, r = tid & 2047;
    int kc = r >> 9, j = (r >> 6) & 7, lane = r & 63;
    int kgrp = lane >> 4, lrow = lane & 15;
    int col = j * 16 + lrow;
    BF8 o;
#pragma unroll
    for (int i = 0; i < 8; ++i) {
        int k = kc * 32 + kgrp * 8 + i;
        o.us[i] = f2bf(W[((size_t)l * DD + k) * DD + col]);
    }
    *(uint4*)&Wf[((size_t)l * 2048 + r) * 8] = o.q;
}

// Wp[col][k] = lin_w[k][col], zero-padded to 48 cols (bf16, K-major)
__global__ void cvtlw_kernel(const float* __restrict__ lw, ushort* __restrict__ Wp) {
    int idx = blockIdx.x * 256 + threadIdx.x;
    if (idx >= 48 * DD) return;
    int col = idx >> 7, k = idx & 127;
    Wp[col * DD + k] = (col < CC) ? f2bf(lw[k * CC + col]) : (ushort)0;
}

// ---------------------------------------------------------------------------
// Y[N,128](bf16) = X[N,128] @ W via fragment-ordered Wf.
// Block 256 = 4 waves; wave owns 16 rows x 128 cols = 8 MFMA 16x16x32 tiles.
// IN32: X is fp32 (layer 0) -> convert in-register, guard the N-tail.
template <int IN32>
__global__ __launch_bounds__(256) void mm_kernel(const void* __restrict__ Xin,
                                                 const ushort* __restrict__ Wf,
                                                 ushort* __restrict__ Y, int N) {
    int wave = threadIdx.x >> 6, lane = threadIdx.x & 63;
    int row0 = blockIdx.x * 64 + wave * 16;
    int lrow = lane & 15, kgrp = lane >> 4;
    int arow = row0 + lrow;

    f32x4 acc[8];
#pragma unroll
    for (int j = 0; j < 8; ++j) acc[j] = (f32x4){0.f, 0.f, 0.f, 0.f};

#pragma unroll
    for (int kc = 0; kc < 4; ++kc) {
        BF8 a;
        if (IN32) {
            if (arow < N) {
                const float* a32 = (const float*)Xin + (size_t)arow * DD + kgrp * 8 + kc * 32;
                float4 f0 = *(const float4*)a32;
                float4 f1 = *(const float4*)(a32 + 4);
                a.us[0] = f2bf(f0.x); a.us[1] = f2bf(f0.y); a.us[2] = f2bf(f0.z); a.us[3] = f2bf(f0.w);
                a.us[4] = f2bf(f1.x); a.us[5] = f2bf(f1.y); a.us[6] = f2bf(f1.z); a.us[7] = f2bf(f1.w);
            } else {
                a.q = make_uint4(0, 0, 0, 0);
            }
        } else {
            // bf16 buffer is padded to NPAD rows; OOB rows feed only unstored outputs
            a.q = *(const uint4*)&((const ushort*)Xin)[(size_t)arow * DD + kgrp * 8 + kc * 32];
        }
#pragma unroll
        for (int j = 0; j < 8; ++j) {
            BF8 b;
            b.q = *(const uint4*)&Wf[(size_t)((kc * 8 + j) * 64 + lane) * 8];
            acc[j] = __builtin_amdgcn_mfma_f32_16x16x32_bf16(a.v, b.v, acc[j], 0, 0, 0);
        }
    }
#pragma unroll
    for (int j = 0; j < 8; ++j) {
        int col = j * 16 + lrow;
#pragma unroll
        for (int r = 0; r < 4; ++r) {
            int row = row0 + kgrp * 4 + r;
            if (row < N) Y[(size_t)row * DD + col] = f2bf(acc[j][r]);
        }
    }
}

// ---------------------------------------------------------------------------
// Fused CSR gather-agg + self loop + bias + BN + ReLU; bf16 in/out, fp32 accum.
// 16 lanes per node (8 ch each); edge loop unrolled x2 with independent
// accumulators so two gather rows are in flight per thread.
__global__ __launch_bounds__(256) void agg_kernel(
    const ushort* __restrict__ h1b, const int* __restrict__ row_ptr,
    const int* __restrict__ csr, const float* __restrict__ dinv,
    const float* __restrict__ bias, const float* __restrict__ gamma,
    const float* __restrict__ beta, const float* __restrict__ mean,
    const float* __restrict__ var, ushort* __restrict__ hout, int N) {
    int gid = (blockIdx.x * blockDim.x + threadIdx.x) >> 4;
    if (gid >= N) return;
    int lane = threadIdx.x & 15;
    int c = lane * 8;

    float acc0[8], acc1[8];
#pragma unroll
    for (int i = 0; i < 8; ++i) { acc0[i] = 0.f; acc1[i] = 0.f; }

    int s = row_ptr[gid], e = row_ptr[gid + 1];
    int p = s;
    for (; p + 2 <= e; p += 2) {
        int s0 = csr[p], s1 = csr[p + 1];
        float w0 = dinv[s0], w1 = dinv[s1];
        BF8 r0, r1;
        r0.q = *(const uint4*)&h1b[(size_t)s0 * DD + c];
        r1.q = *(const uint4*)&h1b[(size_t)s1 * DD + c];
#pragma unroll
        for (int i = 0; i < 8; ++i) {
            acc0[i] = fmaf(w0, bf2f(r0.us[i]), acc0[i]);
            acc1[i] = fmaf(w1, bf2f(r1.us[i]), acc1[i]);
        }
    }
    if (p < e) {
        int s0 = csr[p];
        float w0 = dinv[s0];
        BF8 r0;
        r0.q = *(const uint4*)&h1b[(size_t)s0 * DD + c];
#pragma unroll
        for (int i = 0; i < 8; ++i) acc0[i] = fmaf(w0, bf2f(r0.us[i]), acc0[i]);
    }
#pragma unroll
    for (int i = 0; i < 8; ++i) acc0[i] += acc1[i];

    float di = dinv[gid];
    float sn = di * di;
    BF8 sv;
    sv.q = *(const uint4*)&h1b[(size_t)gid * DD + c];

    float bb[8], gg[8], be[8], mm[8], vv[8];
    *(float4*)&bb[0] = *(const float4*)&bias[c];  *(float4*)&bb[4] = *(const float4*)&bias[c + 4];
    *(float4*)&gg[0] = *(const float4*)&gamma[c]; *(float4*)&gg[4] = *(const float4*)&gamma[c + 4];
    *(float4*)&be[0] = *(const float4*)&beta[c];  *(float4*)&be[4] = *(const float4*)&beta[c + 4];
    *(float4*)&mm[0] = *(const float4*)&mean[c];  *(float4*)&mm[4] = *(const float4*)&mean[c + 4];
    *(float4*)&vv[0] = *(const float4*)&var[c];   *(float4*)&vv[4] = *(const float4*)&var[c + 4];

    BF8 o;
#pragma unroll
    for (int i = 0; i < 8; ++i) {
        float h = fmaf(di, acc0[i], fmaf(sn, bf2f(sv.us[i]), bb[i]));
        float y = fmaxf(gg[i] * (h - mm[i]) * rsqrtf(vv[i] + 1e-5f) + be[i], 0.f);
        o.us[i] = f2bf(y);
    }
    *(uint4*)&hout[(size_t)gid * DD + c] = o.q;
}

// ---------------------------------------------------------------------------
// out = log_softmax( (max_l h_l) @ lin_w + lin_b ). MFMA, zero LDS.
// Wave = 16 nodes; JK-max fused into A-frag loads (integer max, post-ReLU>=0).
__global__ __launch_bounds__(256) void final_kernel(const ushort* __restrict__ hall,
                                                    size_t hstride, int L,
                                                    const ushort* __restrict__ Wp,
                                                    const float* __restrict__ lb,
                                                    float* __restrict__ out, int N) {
    int wave = threadIdx.x >> 6, lane = threadIdx.x & 63;
    int row0 = blockIdx.x * 64 + wave * 16;
    int lrow = lane & 15, kgrp = lane >> 4;
    int arow = row0 + lrow;
    bool rv = arow < N;
    const ushort* abase = &hall[(size_t)arow * DD + kgrp * 8];

    BF8 b[3][4];
#pragma unroll
    for (int j = 0; j < 3; ++j)
#pragma unroll
        for (int kc = 0; kc < 4; ++kc)
            b[j][kc].q = *(const uint4*)&Wp[(size_t)(j * 16 + lrow) * DD + kc * 32 + kgrp * 8];

    f32x4 acc[3];
#pragma unroll
    for (int j = 0; j < 3; ++j) acc[j] = (f32x4){0.f, 0.f, 0.f, 0.f};

#pragma unroll
    for (int kc = 0; kc < 4; ++kc) {
        uint4 m = make_uint4(0, 0, 0, 0);
        if (rv) {
            m = *(const uint4*)&abase[kc * 32];
            for (int l = 1; l < L; ++l)
                m = bfmax4(m, *(const uint4*)&abase[(size_t)l * hstride + kc * 32]);
        }
        BF8 a; a.q = m;
#pragma unroll
        for (int j = 0; j < 3; ++j)
            acc[j] = __builtin_amdgcn_mfma_f32_16x16x32_bf16(a.v, b[j][kc].v, acc[j], 0, 0, 0);
    }

    float lbv[3];
#pragma unroll
    for (int j = 0; j < 3; ++j) {
        int col = j * 16 + lrow;
        lbv[j] = (col < CC) ? lb[col] : 0.f;
    }
#pragma unroll
    for (int r = 0; r < 4; ++r) {
        int node = row0 + kgrp * 4 + r;
        float lg[3];
        float m = -1e30f;
#pragma unroll
        for (int j = 0; j < 3; ++j) {
            int col = j * 16 + lrow;
            float v = (col < CC) ? (acc[j][r] + lbv[j]) : -1e30f;
            lg[j] = v;
            m = fmaxf(m, v);
        }
        m = fmaxf(m, __shfl_xor(m, 1));
        m = fmaxf(m, __shfl_xor(m, 2));
        m = fmaxf(m, __shfl_xor(m, 4));
        m = fmaxf(m, __shfl_xor(m, 8));
        float s = 0.f;
#pragma unroll
        for (int j = 0; j < 3; ++j) {
            int col = j * 16 + lrow;
            if (col < CC) s += expf(lg[j] - m);
        }
        s += __shfl_xor(s, 1);
        s += __shfl_xor(s, 2);
        s += __shfl_xor(s, 4);
        s += __shfl_xor(s, 8);
        float lgs = logf(s);
        if (node < N) {
#pragma unroll
            for (int j = 0; j < 3; ++j) {
                int col = j * 16 + lrow;
                if (col < CC) out[(size_t)node * CC + col] = lg[j] - m - lgs;
            }
        }
    }
}

// ---------------------------------------------------------------------------
extern "C" void kernel_launch(void* const* d_in, const int* in_sizes, int n_in,
                              void* d_out, int out_size, void* d_ws, size_t ws_size,
                              hipStream_t stream) {
    const float* x      = (const float*)d_in[0];
    const void*  eidx   = d_in[1];
    const float* conv_w = (const float*)d_in[2];
    const float* conv_b = (const float*)d_in[3];
    const float* gamma  = (const float*)d_in[4];
    const float* beta   = (const float*)d_in[5];
    const float* mean   = (const float*)d_in[6];
    const float* var    = (const float*)d_in[7];
    const float* lin_w  = (const float*)d_in[8];
    const float* lin_b  = (const float*)d_in[9];
    float* out = (float*)d_out;

    const int N = in_sizes[0] / DD;          // 100000
    const int E = in_sizes[1] / 2;           // 800000
    const int L = in_sizes[3] / DD;          // 5
    const int NPAD = (N + 63) & ~63;         // 100032
    const size_t hstride = (size_t)NPAD * DD;
    const int NB = (N + 1023) / 1024;

    char* p = (char*)d_ws;
    auto alloc = [&](size_t bytes) -> char* {
        char* r = p;
        p += (bytes + 255) & ~(size_t)255;
        return r;
    };
    ushort* xb     = (ushort*)alloc(hstride * 2);            // mm output (per layer)
    ushort* hall   = (ushort*)alloc((size_t)L * hstride * 2);
    ushort* Wf     = (ushort*)alloc((size_t)L * DD * DD * 2);
    ushort* Wp     = (ushort*)alloc((size_t)48 * DD * 2);
    float*  dinv   = (float*)alloc((size_t)N * 4);
    int*    row_ptr= (int*)alloc((size_t)(N + 1) * 4);
    int*    cnt    = (int*)alloc((size_t)N * 4);
    int*    csr    = (int*)alloc((size_t)E * 4);
    int*    blksum = (int*)alloc(128 * 4);
    int*    flag   = (int*)alloc(4);

    detect_kernel<<<1, 64, 0, stream>>>((const unsigned*)eidx, flag);
    hipMemsetAsync(cnt, 0, (size_t)N * 4, stream);
    hist_kernel<<<(E + 255) / 256, 256, 0, stream>>>(eidx, cnt, flag, E);
    scanA_kernel<<<NB, 1024, 0, stream>>>(cnt, row_ptr, dinv, blksum, N);
    scanB_kernel<<<1, 128, 0, stream>>>(blksum, NB);
    scanC_kernel<<<(N + 255) / 256, 256, 0, stream>>>(row_ptr, blksum, N, E);
    scatter_kernel<<<(E + 255) / 256, 256, 0, stream>>>(eidx, row_ptr, cnt, csr, flag, E);

    cvtw_kernel<<<(L * 2048 + 255) / 256, 256, 0, stream>>>(conv_w, Wf, L * 2048);
    cvtlw_kernel<<<(48 * DD + 255) / 256, 256, 0, stream>>>(lin_w, Wp);

    for (int l = 0; l < L; ++l) {
        const ushort* Wl = Wf + (size_t)l * DD * DD;
        if (l == 0)
            mm_kernel<1><<<NPAD / 64, 256, 0, stream>>>(x, Wl, xb, N);
        else
            mm_kernel<0><<<NPAD / 64, 256, 0, stream>>>(hall + (size_t)(l - 1) * hstride, Wl, xb, N);
        ushort* hl = hall + (size_t)l * hstride;
        agg_kernel<<<(int)(((size_t)N * 16 + 255) / 256), 256, 0, stream>>>(
            xb, row_ptr, csr, dinv,
            conv_b + (size_t)l * DD, gamma + (size_t)l * DD, beta + (size_t)l * DD,
            mean + (size_t)l * DD, var + (size_t)l * DD, hl, N);
    }
    final_kernel<<<(N + 63) / 64, 256, 0, stream>>>(hall, hstride, L, Wp, lin_b, out, N);
}

// Round 6
// 406.774 us; speedup vs baseline: 1.5201x; 1.0706x over previous
//
#include <hip/hip_runtime.h>
#include <math.h>

#define DD 128
#define CC 40

typedef __bf16 bf16x8 __attribute__((ext_vector_type(8)));
typedef float f32x4 __attribute__((ext_vector_type(4)));

union BF8 { uint4 q; bf16x8 v; ushort us[8]; };

static __device__ __forceinline__ ushort f2bf(float x) {
    union { float f; unsigned u; } v; v.f = x;
    unsigned r = (v.u + 0x7FFFu + ((v.u >> 16) & 1u)) >> 16;   // RNE
    return (ushort)r;
}
static __device__ __forceinline__ float bf2f(ushort u) {
    union { unsigned u; float f; } v; v.u = ((unsigned)u) << 16;
    return v.f;
}
// per-16-bit unsigned max == bf16 max for non-negative values (post-ReLU)
static __device__ __forceinline__ uint4 bfmax4(uint4 a, uint4 b) {
    union U { uint4 q; ushort us[8]; } x, y;
    x.q = a; y.q = b;
#pragma unroll
    for (int i = 0; i < 8; ++i) x.us[i] = (x.us[i] > y.us[i]) ? x.us[i] : y.us[i];
    return x.q;
}
// byte offset of (row, col_byte) in a 16x256B LDS tile, XOR-swizzled (G4 pattern)
static __device__ __forceinline__ int swz(int row, int colb) {
    return row * 256 + (colb ^ ((row & 7) << 4));
}

// ---------------------------------------------------------------------------
// Detect edge_index storage: int32 vs int64 (odd 32-bit words all zero).
__global__ void detect_kernel(const unsigned* __restrict__ e, int* __restrict__ flag) {
    int t = threadIdx.x;
    unsigned nz = 0;
    for (int j = 0; j < 16; ++j) nz |= e[2 * (t * 16 + j) + 1];
    unsigned long long b = __ballot(nz != 0);
    if (t == 0) *flag = (b != 0) ? 1 : 0;
}

// non-temporal edge fetch: don't let the 12.8MB eidx stream evict csr/cursor from L2
__device__ __forceinline__ int edge_at_nt(const void* eptr, int is32, long long idx) {
    if (is32) return __builtin_nontemporal_load((const int*)eptr + idx);
    return (int)__builtin_nontemporal_load((const long long*)eptr + idx);
}

__global__ void hist_kernel(const void* __restrict__ eptr, int* __restrict__ cnt,
                            const int* __restrict__ flag, int E) {
    int e = blockIdx.x * blockDim.x + threadIdx.x;
    if (e >= E) return;
    int is32 = *flag;
    int r = edge_at_nt(eptr, is32, e);
    atomicAdd(&cnt[r], 1);
}

// Hierarchical exclusive scan (1024/block): local scan + block sums.
__global__ __launch_bounds__(1024) void scanA_kernel(int* __restrict__ cnt,
                                                     int* __restrict__ row_ptr,
                                                     float* __restrict__ dinv,
                                                     int* __restrict__ blksum, int N) {
    __shared__ int swave[16];
    int tid = threadIdx.x;
    int lane = tid & 63, wid = tid >> 6;
    int i = blockIdx.x * 1024 + tid;
    int v = (i < N) ? cnt[i] : 0;
    int incl = v;
#pragma unroll
    for (int off = 1; off < 64; off <<= 1) {
        int t = __shfl_up(incl, off);
        if (lane >= off) incl += t;
    }
    if (lane == 63) swave[wid] = incl;
    __syncthreads();
    if (tid < 16) {
        int t = swave[tid];
#pragma unroll
        for (int off = 1; off < 16; off <<= 1) {
            int u = __shfl_up(t, off);
            if (tid >= off) t += u;
        }
        swave[tid] = t;
    }
    __syncthreads();
    int waveoff = (wid == 0) ? 0 : swave[wid - 1];
    if (i < N) {
        row_ptr[i] = waveoff + incl - v;
        dinv[i] = rsqrtf((float)v + 1.0f);
        cnt[i] = 0;
    }
    if (tid == 0) blksum[blockIdx.x] = swave[15];
}

__global__ __launch_bounds__(128) void scanB_kernel(int* __restrict__ blksum, int nb) {
    __shared__ int s[128];
    int t = threadIdx.x;
    int orig = (t < nb) ? blksum[t] : 0;
    s[t] = orig;
    __syncthreads();
    for (int off = 1; off < 128; off <<= 1) {
        int v = (t >= off) ? s[t - off] : 0;
        __syncthreads();
        s[t] += v;
        __syncthreads();
    }
    if (t < nb) blksum[t] = s[t] - orig;
}

__global__ void scanC_kernel(int* __restrict__ row_ptr, const int* __restrict__ blksum,
                             int N, int E) {
    int i = blockIdx.x * blockDim.x + threadIdx.x;
    if (i < N) row_ptr[i] += blksum[i >> 10];
    if (i == 0) row_ptr[N] = E;
}

__global__ void scatter_kernel(const void* __restrict__ eptr, const int* __restrict__ row_ptr,
                               int* __restrict__ cursor, int* __restrict__ csr,
                               const int* __restrict__ flag, int E) {
    int e = blockIdx.x * blockDim.x + threadIdx.x;
    if (e >= E) return;
    int is32 = *flag;
    int r = edge_at_nt(eptr, is32, e);
    int c = edge_at_nt(eptr, is32, (long long)E + e);
    int pos = row_ptr[r] + atomicAdd(&cursor[r], 1);
    csr[pos] = c;
}

// ---------------------------------------------------------------------------
// Wf: MFMA-fragment-ordered conv weights (B-frag load = base + lane*16B).
__global__ void cvtw_kernel(const float* __restrict__ W, ushort* __restrict__ Wf, int total) {
    int tid = blockIdx.x * 256 + threadIdx.x;
    if (tid >= total) return;                      // total = L * 2048
    int l = tid >> 11, r = tid & 2047;
    int kc = r >> 9, j = (r >> 6) & 7, lane = r & 63;
    int kgrp = lane >> 4, lrow = lane & 15;
    int col = j * 16 + lrow;
    BF8 o;
#pragma unroll
    for (int i = 0; i < 8; ++i) {
        int k = kc * 32 + kgrp * 8 + i;
        o.us[i] = f2bf(W[((size_t)l * DD + k) * DD + col]);
    }
    *(uint4*)&Wf[((size_t)l * 2048 + r) * 8] = o.q;
}

// Wpf: fragment-ordered lin_w, zero-padded to 48 cols. frag f = kc*3+j.
__global__ void cvtlw_kernel(const float* __restrict__ lw, ushort* __restrict__ Wpf) {
    int tid = blockIdx.x * 256 + threadIdx.x;
    if (tid >= 12 * 64) return;
    int f = tid >> 6, lane = tid & 63;
    int kc = f / 3, j = f % 3;
    int kgrp = lane >> 4, lrow = lane & 15;
    int col = j * 16 + lrow;
    BF8 o;
#pragma unroll
    for (int i = 0; i < 8; ++i) {
        int k = kc * 32 + kgrp * 8 + i;
        o.us[i] = (col < CC) ? f2bf(lw[k * CC + col]) : (ushort)0;
    }
    *(uint4*)&Wpf[(size_t)tid * 8] = o.q;
}

// ---------------------------------------------------------------------------
// Y[N,128](bf16) = X[N,128] @ W via fragment-ordered Wf.
// Block 256 = 4 waves; wave owns 16 rows x 128 cols = 8 MFMA 16x16x32 tiles.
// bf16 A path: 4 contiguous 1KB loads -> swizzled LDS -> frag reads.
// Epilogue: acc -> swizzled LDS -> 4 contiguous 1KB stores.
template <int IN32>
__global__ __launch_bounds__(256) void mm_kernel(const void* __restrict__ Xin,
                                                 const ushort* __restrict__ Wf,
                                                 ushort* __restrict__ Y, int N) {
    __shared__ char slab[4][4096];
    int wave = threadIdx.x >> 6, lane = threadIdx.x & 63;
    int row0 = blockIdx.x * 64 + wave * 16;
    int lrow = lane & 15, kgrp = lane >> 4;
    char* sw = slab[wave];
    size_t tbase = (size_t)row0 * DD;
    int srow = (lane >> 4);            // staging row group
    int scolb = (lane & 15) * 16;      // staging col byte

    BF8 a[4];
    if (IN32) {
        int arow = row0 + lrow;
#pragma unroll
        for (int kc = 0; kc < 4; ++kc) {
            if (arow < N) {
                const float* a32 = (const float*)Xin + (size_t)arow * DD + kgrp * 8 + kc * 32;
                float4 f0 = *(const float4*)a32;
                float4 f1 = *(const float4*)(a32 + 4);
                a[kc].us[0] = f2bf(f0.x); a[kc].us[1] = f2bf(f0.y);
                a[kc].us[2] = f2bf(f0.z); a[kc].us[3] = f2bf(f0.w);
                a[kc].us[4] = f2bf(f1.x); a[kc].us[5] = f2bf(f1.y);
                a[kc].us[6] = f2bf(f1.z); a[kc].us[7] = f2bf(f1.w);
            } else {
                a[kc].q = make_uint4(0, 0, 0, 0);
            }
        }
    } else {
        const ushort* Xb = (const ushort*)Xin;   // NPAD-padded
#pragma unroll
        for (int i = 0; i < 4; ++i) {
            uint4 v = *(const uint4*)&Xb[tbase + i * 512 + lane * 8];
            int row = i * 4 + srow;
            *(uint4*)(sw + swz(row, scolb)) = v;
        }
#pragma unroll
        for (int kc = 0; kc < 4; ++kc)
            a[kc].q = *(const uint4*)(sw + swz(lrow, kgrp * 16 + kc * 64));
    }

    f32x4 acc[8];
#pragma unroll
    for (int j = 0; j < 8; ++j) acc[j] = (f32x4){0.f, 0.f, 0.f, 0.f};

#pragma unroll
    for (int kc = 0; kc < 4; ++kc) {
#pragma unroll
        for (int j = 0; j < 8; ++j) {
            BF8 b;
            b.q = *(const uint4*)&Wf[(size_t)((kc * 8 + j) * 64 + lane) * 8];
            acc[j] = __builtin_amdgcn_mfma_f32_16x16x32_bf16(a[kc].v, b.v, acc[j], 0, 0, 0);
        }
    }

    // epilogue: stage to LDS in row form, store contiguous
#pragma unroll
    for (int j = 0; j < 8; ++j) {
        int colb = (j * 16 + lrow) * 2;
#pragma unroll
        for (int r = 0; r < 4; ++r) {
            int row = kgrp * 4 + r;
            *(ushort*)(sw + swz(row, colb)) = f2bf(acc[j][r]);
        }
    }
#pragma unroll
    for (int i = 0; i < 4; ++i) {
        int row = i * 4 + srow;
        uint4 o = *(const uint4*)(sw + swz(row, scolb));
        int grow = row0 + row;
        if (grow < N) *(uint4*)&Y[tbase + i * 512 + lane * 8] = o;
    }
}

// ---------------------------------------------------------------------------
// Fused CSR gather-agg + self loop + bias + BN + ReLU; bf16 in/out, fp32 accum.
// 16 lanes per node (8 ch each); edge loop unrolled x2.
__global__ __launch_bounds__(256) void agg_kernel(
    const ushort* __restrict__ h1b, const int* __restrict__ row_ptr,
    const int* __restrict__ csr, const float* __restrict__ dinv,
    const float* __restrict__ bias, const float* __restrict__ gamma,
    const float* __restrict__ beta, const float* __restrict__ mean,
    const float* __restrict__ var, ushort* __restrict__ hout, int N) {
    int gid = (blockIdx.x * blockDim.x + threadIdx.x) >> 4;
    if (gid >= N) return;
    int lane = threadIdx.x & 15;
    int c = lane * 8;

    float acc0[8], acc1[8];
#pragma unroll
    for (int i = 0; i < 8; ++i) { acc0[i] = 0.f; acc1[i] = 0.f; }

    int s = row_ptr[gid], e = row_ptr[gid + 1];
    int p = s;
    for (; p + 2 <= e; p += 2) {
        int s0 = csr[p], s1 = csr[p + 1];
        float w0 = dinv[s0], w1 = dinv[s1];
        BF8 r0, r1;
        r0.q = *(const uint4*)&h1b[(size_t)s0 * DD + c];
        r1.q = *(const uint4*)&h1b[(size_t)s1 * DD + c];
#pragma unroll
        for (int i = 0; i < 8; ++i) {
            acc0[i] = fmaf(w0, bf2f(r0.us[i]), acc0[i]);
            acc1[i] = fmaf(w1, bf2f(r1.us[i]), acc1[i]);
        }
    }
    if (p < e) {
        int s0 = csr[p];
        float w0 = dinv[s0];
        BF8 r0;
        r0.q = *(const uint4*)&h1b[(size_t)s0 * DD + c];
#pragma unroll
        for (int i = 0; i < 8; ++i) acc0[i] = fmaf(w0, bf2f(r0.us[i]), acc0[i]);
    }
#pragma unroll
    for (int i = 0; i < 8; ++i) acc0[i] += acc1[i];

    float di = dinv[gid];
    float sn = di * di;
    BF8 sv;
    sv.q = *(const uint4*)&h1b[(size_t)gid * DD + c];

    float bb[8], gg[8], be[8], mm[8], vv[8];
    *(float4*)&bb[0] = *(const float4*)&bias[c];  *(float4*)&bb[4] = *(const float4*)&bias[c + 4];
    *(float4*)&gg[0] = *(const float4*)&gamma[c]; *(float4*)&gg[4] = *(const float4*)&gamma[c + 4];
    *(float4*)&be[0] = *(const float4*)&beta[c];  *(float4*)&be[4] = *(const float4*)&beta[c + 4];
    *(float4*)&mm[0] = *(const float4*)&mean[c];  *(float4*)&mm[4] = *(const float4*)&mean[c + 4];
    *(float4*)&vv[0] = *(const float4*)&var[c];   *(float4*)&vv[4] = *(const float4*)&var[c + 4];

    BF8 o;
#pragma unroll
    for (int i = 0; i < 8; ++i) {
        float h = fmaf(di, acc0[i], fmaf(sn, bf2f(sv.us[i]), bb[i]));
        float y = fmaxf(gg[i] * (h - mm[i]) * rsqrtf(vv[i] + 1e-5f) + be[i], 0.f);
        o.us[i] = f2bf(y);
    }
    *(uint4*)&hout[(size_t)gid * DD + c] = o.q;
}

// ---------------------------------------------------------------------------
// out = log_softmax( (max_l h_l) @ lin_w + lin_b ). MFMA.
// JK-max on contiguous 1KB loads -> swizzled LDS -> A frags.
__global__ __launch_bounds__(256) void final_kernel(const ushort* __restrict__ hall,
                                                    size_t hstride, int L,
                                                    const ushort* __restrict__ Wpf,
                                                    const float* __restrict__ lb,
                                                    float* __restrict__ out, int N) {
    __shared__ char slab[4][4096];
    int wave = threadIdx.x >> 6, lane = threadIdx.x & 63;
    int row0 = blockIdx.x * 64 + wave * 16;
    int lrow = lane & 15, kgrp = lane >> 4;
    char* sw = slab[wave];
    size_t tbase = (size_t)row0 * DD;
    int srow = lane >> 4;
    int scolb = (lane & 15) * 16;

    // stage JK-max tile (16 rows x 256B), fully-coalesced loads
#pragma unroll
    for (int i = 0; i < 4; ++i) {
        const ushort* pp = &hall[tbase + i * 512 + lane * 8];
        uint4 m = *(const uint4*)pp;
        for (int l = 1; l < L; ++l)
            m = bfmax4(m, *(const uint4*)(pp + (size_t)l * hstride));
        int row = i * 4 + srow;
        *(uint4*)(sw + swz(row, scolb)) = m;
    }

    BF8 a[4];
#pragma unroll
    for (int kc = 0; kc < 4; ++kc)
        a[kc].q = *(const uint4*)(sw + swz(lrow, kgrp * 16 + kc * 64));

    f32x4 acc[3];
#pragma unroll
    for (int j = 0; j < 3; ++j) acc[j] = (f32x4){0.f, 0.f, 0.f, 0.f};
#pragma unroll
    for (int kc = 0; kc < 4; ++kc) {
#pragma unroll
        for (int j = 0; j < 3; ++j) {
            BF8 b;
            b.q = *(const uint4*)&Wpf[(size_t)((kc * 3 + j) * 64 + lane) * 8];
            acc[j] = __builtin_amdgcn_mfma_f32_16x16x32_bf16(a[kc].v, b.v, acc[j], 0, 0, 0);
        }
    }

    float lbv[3];
#pragma unroll
    for (int j = 0; j < 3; ++j) {
        int col = j * 16 + lrow;
        lbv[j] = (col < CC) ? lb[col] : 0.f;
    }
#pragma unroll
    for (int r = 0; r < 4; ++r) {
        int node = row0 + kgrp * 4 + r;
        float lg[3];
        float m = -1e30f;
#pragma unroll
        for (int j = 0; j < 3; ++j) {
            int col = j * 16 + lrow;
            float v = (col < CC) ? (acc[j][r] + lbv[j]) : -1e30f;
            lg[j] = v;
            m = fmaxf(m, v);
        }
        m = fmaxf(m, __shfl_xor(m, 1));
        m = fmaxf(m, __shfl_xor(m, 2));
        m = fmaxf(m, __shfl_xor(m, 4));
        m = fmaxf(m, __shfl_xor(m, 8));
        float s = 0.f;
#pragma unroll
        for (int j = 0; j < 3; ++j) {
            int col = j * 16 + lrow;
            if (col < CC) s += expf(lg[j] - m);
        }
        s += __shfl_xor(s, 1);
        s += __shfl_xor(s, 2);
        s += __shfl_xor(s, 4);
        s += __shfl_xor(s, 8);
        float lgs = logf(s);
        if (node < N) {
#pragma unroll
            for (int j = 0; j < 3; ++j) {
                int col = j * 16 + lrow;
                if (col < CC) out[(size_t)node * CC + col] = lg[j] - m - lgs;
            }
        }
    }
}

// ---------------------------------------------------------------------------
extern "C" void kernel_launch(void* const* d_in, const int* in_sizes, int n_in,
                              void* d_out, int out_size, void* d_ws, size_t ws_size,
                              hipStream_t stream) {
    const float* x      = (const float*)d_in[0];
    const void*  eidx   = d_in[1];
    const float* conv_w = (const float*)d_in[2];
    const float* conv_b = (const float*)d_in[3];
    const float* gamma  = (const float*)d_in[4];
    const float* beta   = (const float*)d_in[5];
    const float* mean   = (const float*)d_in[6];
    const float* var    = (const float*)d_in[7];
    const float* lin_w  = (const float*)d_in[8];
    const float* lin_b  = (const float*)d_in[9];
    float* out = (float*)d_out;

    const int N = in_sizes[0] / DD;          // 100000
    const int E = in_sizes[1] / 2;           // 800000
    const int L = in_sizes[3] / DD;          // 5
    const int NPAD = (N + 63) & ~63;         // 100032
    const size_t hstride = (size_t)NPAD * DD;
    const int NB = (N + 1023) / 1024;

    char* p = (char*)d_ws;
    auto alloc = [&](size_t bytes) -> char* {
        char* r = p;
        p += (bytes + 255) & ~(size_t)255;
        return r;
    };
    ushort* xb     = (ushort*)alloc(hstride * 2);            // mm output (per layer)
    ushort* hall   = (ushort*)alloc((size_t)L * hstride * 2);
    ushort* Wf     = (ushort*)alloc((size_t)L * DD * DD * 2);
    ushort* Wpf    = (ushort*)alloc((size_t)12 * 64 * 8 * 2);
    float*  dinv   = (float*)alloc((size_t)N * 4);
    int*    row_ptr= (int*)alloc((size_t)(N + 1) * 4);
    int*    cnt    = (int*)alloc((size_t)N * 4);
    int*    csr    = (int*)alloc((size_t)E * 4);
    int*    blksum = (int*)alloc(128 * 4);
    int*    flag   = (int*)alloc(4);

    detect_kernel<<<1, 64, 0, stream>>>((const unsigned*)eidx, flag);
    hipMemsetAsync(cnt, 0, (size_t)N * 4, stream);
    hist_kernel<<<(E + 255) / 256, 256, 0, stream>>>(eidx, cnt, flag, E);
    scanA_kernel<<<NB, 1024, 0, stream>>>(cnt, row_ptr, dinv, blksum, N);
    scanB_kernel<<<1, 128, 0, stream>>>(blksum, NB);
    scanC_kernel<<<(N + 255) / 256, 256, 0, stream>>>(row_ptr, blksum, N, E);
    scatter_kernel<<<(E + 255) / 256, 256, 0, stream>>>(eidx, row_ptr, cnt, csr, flag, E);

    cvtw_kernel<<<(L * 2048 + 255) / 256, 256, 0, stream>>>(conv_w, Wf, L * 2048);
    cvtlw_kernel<<<3, 256, 0, stream>>>(lin_w, Wpf);

    for (int l = 0; l < L; ++l) {
        const ushort* Wl = Wf + (size_t)l * DD * DD;
        if (l == 0)
            mm_kernel<1><<<NPAD / 64, 256, 0, stream>>>(x, Wl, xb, N);
        else
            mm_kernel<0><<<NPAD / 64, 256, 0, stream>>>(hall + (size_t)(l - 1) * hstride, Wl, xb, N);
        ushort* hl = hall + (size_t)l * hstride;
        agg_kernel<<<(int)(((size_t)N * 16 + 255) / 256), 256, 0, stream>>>(
            xb, row_ptr, csr, dinv,
            conv_b + (size_t)l * DD, gamma + (size_t)l * DD, beta + (size_t)l * DD,
            mean + (size_t)l * DD, var + (size_t)l * DD, hl, N);
    }
    final_kernel<<<(N + 63) / 64, 256, 0, stream>>>(hall, hstride, L, Wpf, lin_b, out, N);
}

// Round 7
// 388.137 us; speedup vs baseline: 1.5931x; 1.0480x over previous
//
#include <hip/hip_runtime.h>
#include <math.h>

#define DD 128
#define CC 40
#define BSH 9          // bucket shift: 512 nodes/bucket
#define BSZ 512

typedef __bf16 bf16x8 __attribute__((ext_vector_type(8)));
typedef float f32x4 __attribute__((ext_vector_type(4)));

union BF8 { uint4 q; bf16x8 v; ushort us[8]; };

static __device__ __forceinline__ ushort f2bf(float x) {
    union { float f; unsigned u; } v; v.f = x;
    unsigned r = (v.u + 0x7FFFu + ((v.u >> 16) & 1u)) >> 16;   // RNE
    return (ushort)r;
}
static __device__ __forceinline__ float bf2f(ushort u) {
    union { unsigned u; float f; } v; v.u = ((unsigned)u) << 16;
    return v.f;
}
// per-16-bit unsigned max == bf16 max for non-negative values (post-ReLU)
static __device__ __forceinline__ uint4 bfmax4(uint4 a, uint4 b) {
    union U { uint4 q; ushort us[8]; } x, y;
    x.q = a; y.q = b;
#pragma unroll
    for (int i = 0; i < 8; ++i) x.us[i] = (x.us[i] > y.us[i]) ? x.us[i] : y.us[i];
    return x.q;
}
// byte offset of (row, col_byte) in a 16x256B LDS tile, XOR-swizzled (G4 pattern)
static __device__ __forceinline__ int swz(int row, int colb) {
    return row * 256 + (colb ^ ((row & 7) << 4));
}

// ---------------------------------------------------------------------------
__global__ void detect_kernel(const unsigned* __restrict__ e, int* __restrict__ flag) {
    int t = threadIdx.x;
    unsigned nz = 0;
    for (int j = 0; j < 16; ++j) nz |= e[2 * (t * 16 + j) + 1];
    unsigned long long b = __ballot(nz != 0);
    if (t == 0) *flag = (b != 0) ? 1 : 0;
}

__device__ __forceinline__ int edge_at_nt(const void* eptr, int is32, long long idx) {
    if (is32) return __builtin_nontemporal_load((const int*)eptr + idx);
    return (int)__builtin_nontemporal_load((const long long*)eptr + idx);
}

__global__ void hist_kernel(const void* __restrict__ eptr, int* __restrict__ cnt,
                            const int* __restrict__ flag, int E) {
    int e = blockIdx.x * blockDim.x + threadIdx.x;
    if (e >= E) return;
    int is32 = *flag;
    int r = edge_at_nt(eptr, is32, e);
    atomicAdd(&cnt[r], 1);
}

// Hierarchical exclusive scan (1024/block).
__global__ __launch_bounds__(1024) void scanA_kernel(int* __restrict__ cnt,
                                                     int* __restrict__ row_ptr,
                                                     float* __restrict__ dinv,
                                                     int* __restrict__ blksum, int N) {
    __shared__ int swave[16];
    int tid = threadIdx.x;
    int lane = tid & 63, wid = tid >> 6;
    int i = blockIdx.x * 1024 + tid;
    int v = (i < N) ? cnt[i] : 0;
    int incl = v;
#pragma unroll
    for (int off = 1; off < 64; off <<= 1) {
        int t = __shfl_up(incl, off);
        if (lane >= off) incl += t;
    }
    if (lane == 63) swave[wid] = incl;
    __syncthreads();
    if (tid < 16) {
        int t = swave[tid];
#pragma unroll
        for (int off = 1; off < 16; off <<= 1) {
            int u = __shfl_up(t, off);
            if (tid >= off) t += u;
        }
        swave[tid] = t;
    }
    __syncthreads();
    int waveoff = (wid == 0) ? 0 : swave[wid - 1];
    if (i < N) {
        row_ptr[i] = waveoff + incl - v;
        dinv[i] = rsqrtf((float)v + 1.0f);
    }
    if (tid == 0) blksum[blockIdx.x] = swave[15];
}

__global__ __launch_bounds__(128) void scanB_kernel(int* __restrict__ blksum, int nb) {
    __shared__ int s[128];
    int t = threadIdx.x;
    int orig = (t < nb) ? blksum[t] : 0;
    s[t] = orig;
    __syncthreads();
    for (int off = 1; off < 128; off <<= 1) {
        int v = (t >= off) ? s[t - off] : 0;
        __syncthreads();
        s[t] += v;
        __syncthreads();
    }
    if (t < nb) blksum[t] = s[t] - orig;
}

__global__ void scanC_kernel(int* __restrict__ row_ptr, const int* __restrict__ blksum,
                             int N, int E) {
    int i = blockIdx.x * blockDim.x + threadIdx.x;
    if (i < N) row_ptr[i] += blksum[i >> 10];
    if (i == 0) row_ptr[N] = E;
}

// gcursor[b] = row_ptr[b*BSZ]  (bucket regions in bins[] are exact)
__global__ void initcur_kernel(const int* __restrict__ row_ptr, int* __restrict__ gcursor,
                               int nbk) {
    int b = blockIdx.x * blockDim.x + threadIdx.x;
    if (b < nbk) gcursor[b] = row_ptr[(size_t)b << BSH];
}

// ---------------------------------------------------------------------------
// Bin pass: block = 4096 edges; LDS histogram over buckets; one global
// atomicAdd per (block,bucket); pairs written in contiguous per-bucket runs.
__global__ __launch_bounds__(256) void bin_kernel(const void* __restrict__ eptr,
                                                  const int* __restrict__ flag,
                                                  int* __restrict__ gcursor,
                                                  unsigned long long* __restrict__ bins,
                                                  int E, int nbk) {
    __shared__ int lcount[256];
    __shared__ int gbase[256];
    int t = threadIdx.x;
    lcount[t] = 0;
    __syncthreads();
    int is32 = *flag;
    long base = (long)blockIdx.x * 4096;
    int r[16], c[16], slot[16];
#pragma unroll
    for (int i = 0; i < 16; ++i) {
        long e = base + i * 256 + t;
        if (e < E) {
            r[i] = edge_at_nt(eptr, is32, e);
            c[i] = edge_at_nt(eptr, is32, (long long)E + e);
            slot[i] = atomicAdd(&lcount[r[i] >> BSH], 1);
        } else {
            r[i] = -1;
        }
    }
    __syncthreads();
    if (t < nbk && lcount[t] > 0) gbase[t] = atomicAdd(&gcursor[t], lcount[t]);
    __syncthreads();
#pragma unroll
    for (int i = 0; i < 16; ++i) {
        if (r[i] >= 0) {
            int b = r[i] >> BSH;
            bins[(size_t)gbase[b] + slot[i]] =
                ((unsigned long long)(unsigned)c[i] << 32) | (unsigned)r[i];
        }
    }
}

// Bucket scatter: one block per bucket; cursors in LDS; csr writes stay in
// a <=20KB L2-resident slice.
__global__ __launch_bounds__(256) void bscatter_kernel(const unsigned long long* __restrict__ bins,
                                                       const int* __restrict__ row_ptr,
                                                       int* __restrict__ csr, int N) {
    __shared__ int lcur[BSZ];
    int node0 = blockIdx.x << BSH;
    int nend = node0 + BSZ; if (nend > N) nend = N;
    for (int i = threadIdx.x; i < BSZ; i += 256) lcur[i] = 0;
    __syncthreads();
    int s = row_ptr[node0], e = row_ptr[nend];
    for (int p = s + threadIdx.x; p < e; p += 256) {
        unsigned long long pr = bins[p];
        int r = (int)(pr & 0xffffffffu);
        int c = (int)(pr >> 32);
        int pos = row_ptr[r] + atomicAdd(&lcur[r - node0], 1);
        csr[pos] = c;
    }
}

// ---------------------------------------------------------------------------
// Wf: MFMA-fragment-ordered conv weights (B-frag load = base + lane*16B).
__global__ void cvtw_kernel(const float* __restrict__ W, ushort* __restrict__ Wf, int total) {
    int tid = blockIdx.x * 256 + threadIdx.x;
    if (tid >= total) return;                      // total = L * 2048
    int l = tid >> 11, r = tid & 2047;
    int kc = r >> 9, j = (r >> 6) & 7, lane = r & 63;
    int kgrp = lane >> 4, lrow = lane & 15;
    int col = j * 16 + lrow;
    BF8 o;
#pragma unroll
    for (int i = 0; i < 8; ++i) {
        int k = kc * 32 + kgrp * 8 + i;
        o.us[i] = f2bf(W[((size_t)l * DD + k) * DD + col]);
    }
    *(uint4*)&Wf[((size_t)l * 2048 + r) * 8] = o.q;
}

// Wpf: fragment-ordered lin_w, zero-padded to 48 cols. frag f = kc*3+j.
__global__ void cvtlw_kernel(const float* __restrict__ lw, ushort* __restrict__ Wpf) {
    int tid = blockIdx.x * 256 + threadIdx.x;
    if (tid >= 12 * 64) return;
    int f = tid >> 6, lane = tid & 63;
    int kc = f / 3, j = f % 3;
    int kgrp = lane >> 4, lrow = lane & 15;
    int col = j * 16 + lrow;
    BF8 o;
#pragma unroll
    for (int i = 0; i < 8; ++i) {
        int k = kc * 32 + kgrp * 8 + i;
        o.us[i] = (col < CC) ? f2bf(lw[k * CC + col]) : (ushort)0;
    }
    *(uint4*)&Wpf[(size_t)tid * 8] = o.q;
}

// ---------------------------------------------------------------------------
// Y[N,128](bf16) = dinv[row] * (X[N,128] @ W)  via fragment-ordered Wf.
// Block 256 = 4 waves; wave owns 16 rows x 128 cols = 8 MFMA 16x16x32 tiles.
template <int IN32>
__global__ __launch_bounds__(256) void mm_kernel(const void* __restrict__ Xin,
                                                 const ushort* __restrict__ Wf,
                                                 const float* __restrict__ dinv,
                                                 ushort* __restrict__ Y, int N) {
    __shared__ char slab[4][4096];
    int wave = threadIdx.x >> 6, lane = threadIdx.x & 63;
    int row0 = blockIdx.x * 64 + wave * 16;
    int lrow = lane & 15, kgrp = lane >> 4;
    char* sw = slab[wave];
    size_t tbase = (size_t)row0 * DD;
    int srow = (lane >> 4);            // staging row group
    int scolb = (lane & 15) * 16;      // staging col byte

    BF8 a[4];
    if (IN32) {
        int arow = row0 + lrow;
#pragma unroll
        for (int kc = 0; kc < 4; ++kc) {
            if (arow < N) {
                const float* a32 = (const float*)Xin + (size_t)arow * DD + kgrp * 8 + kc * 32;
                float4 f0 = *(const float4*)a32;
                float4 f1 = *(const float4*)(a32 + 4);
                a[kc].us[0] = f2bf(f0.x); a[kc].us[1] = f2bf(f0.y);
                a[kc].us[2] = f2bf(f0.z); a[kc].us[3] = f2bf(f0.w);
                a[kc].us[4] = f2bf(f1.x); a[kc].us[5] = f2bf(f1.y);
                a[kc].us[6] = f2bf(f1.z); a[kc].us[7] = f2bf(f1.w);
            } else {
                a[kc].q = make_uint4(0, 0, 0, 0);
            }
        }
    } else {
        const ushort* Xb = (const ushort*)Xin;   // NPAD-padded
#pragma unroll
        for (int i = 0; i < 4; ++i) {
            uint4 v = *(const uint4*)&Xb[tbase + i * 512 + lane * 8];
            int row = i * 4 + srow;
            *(uint4*)(sw + swz(row, scolb)) = v;
        }
#pragma unroll
        for (int kc = 0; kc < 4; ++kc)
            a[kc].q = *(const uint4*)(sw + swz(lrow, kgrp * 16 + kc * 64));
    }

    f32x4 acc[8];
#pragma unroll
    for (int j = 0; j < 8; ++j) acc[j] = (f32x4){0.f, 0.f, 0.f, 0.f};

#pragma unroll
    for (int kc = 0; kc < 4; ++kc) {
#pragma unroll
        for (int j = 0; j < 8; ++j) {
            BF8 b;
            b.q = *(const uint4*)&Wf[(size_t)((kc * 8 + j) * 64 + lane) * 8];
            acc[j] = __builtin_amdgcn_mfma_f32_16x16x32_bf16(a[kc].v, b.v, acc[j], 0, 0, 0);
        }
    }

    // pre-scale rows by dinv -> hs = dinv * (X@W)
    float dv[4];
#pragma unroll
    for (int r = 0; r < 4; ++r) {
        int row = row0 + kgrp * 4 + r;
        dv[r] = dinv[row < N ? row : (N - 1)];
    }

    // epilogue: stage to LDS in row form, store contiguous
#pragma unroll
    for (int j = 0; j < 8; ++j) {
        int colb = (j * 16 + lrow) * 2;
#pragma unroll
        for (int r = 0; r < 4; ++r) {
            int row = kgrp * 4 + r;
            *(ushort*)(sw + swz(row, colb)) = f2bf(acc[j][r] * dv[r]);
        }
    }
#pragma unroll
    for (int i = 0; i < 4; ++i) {
        int row = i * 4 + srow;
        uint4 o = *(const uint4*)(sw + swz(row, scolb));
        int grow = row0 + row;
        if (grow < N) *(uint4*)&Y[tbase + i * 512 + lane * 8] = o;
    }
}

// ---------------------------------------------------------------------------
// Fused CSR gather-agg (+self fold) + bias + BN + ReLU on pre-scaled hs.
// h = dinv_i * (sum_src hs_src + hs_i) + b; 16 lanes/node, unroll-4.
__global__ __launch_bounds__(256) void agg_kernel(
    const ushort* __restrict__ hs, const int* __restrict__ row_ptr,
    const int* __restrict__ csr, const float* __restrict__ dinv,
    const float* __restrict__ bias, const float* __restrict__ gamma,
    const float* __restrict__ beta, const float* __restrict__ mean,
    const float* __restrict__ var, ushort* __restrict__ hout, int N) {
    int gid = (blockIdx.x * blockDim.x + threadIdx.x) >> 4;
    if (gid >= N) return;
    int lane = threadIdx.x & 15;
    int c = lane * 8;

    float acc0[8], acc1[8], acc2[8], acc3[8];
    BF8 sv;
    sv.q = *(const uint4*)&hs[(size_t)gid * DD + c];   // self (pre-scaled)
#pragma unroll
    for (int i = 0; i < 8; ++i) {
        acc0[i] = bf2f(sv.us[i]);
        acc1[i] = 0.f; acc2[i] = 0.f; acc3[i] = 0.f;
    }

    int s = row_ptr[gid], e = row_ptr[gid + 1];
    int p = s;
    for (; p + 4 <= e; p += 4) {
        int s0 = csr[p], s1 = csr[p + 1], s2 = csr[p + 2], s3 = csr[p + 3];
        BF8 r0, r1, r2, r3;
        r0.q = *(const uint4*)&hs[(size_t)s0 * DD + c];
        r1.q = *(const uint4*)&hs[(size_t)s1 * DD + c];
        r2.q = *(const uint4*)&hs[(size_t)s2 * DD + c];
        r3.q = *(const uint4*)&hs[(size_t)s3 * DD + c];
#pragma unroll
        for (int i = 0; i < 8; ++i) {
            acc0[i] += bf2f(r0.us[i]);
            acc1[i] += bf2f(r1.us[i]);
            acc2[i] += bf2f(r2.us[i]);
            acc3[i] += bf2f(r3.us[i]);
        }
    }
    for (; p < e; ++p) {
        int s0 = csr[p];
        BF8 r0;
        r0.q = *(const uint4*)&hs[(size_t)s0 * DD + c];
#pragma unroll
        for (int i = 0; i < 8; ++i) acc0[i] += bf2f(r0.us[i]);
    }
#pragma unroll
    for (int i = 0; i < 8; ++i) acc0[i] += acc1[i] + acc2[i] + acc3[i];

    float di = dinv[gid];

    float bb[8], gg[8], be[8], mm[8], vv[8];
    *(float4*)&bb[0] = *(const float4*)&bias[c];  *(float4*)&bb[4] = *(const float4*)&bias[c + 4];
    *(float4*)&gg[0] = *(const float4*)&gamma[c]; *(float4*)&gg[4] = *(const float4*)&gamma[c + 4];
    *(float4*)&be[0] = *(const float4*)&beta[c];  *(float4*)&be[4] = *(const float4*)&beta[c + 4];
    *(float4*)&mm[0] = *(const float4*)&mean[c];  *(float4*)&mm[4] = *(const float4*)&mean[c + 4];
    *(float4*)&vv[0] = *(const float4*)&var[c];   *(float4*)&vv[4] = *(const float4*)&var[c + 4];

    BF8 o;
#pragma unroll
    for (int i = 0; i < 8; ++i) {
        float h = fmaf(di, acc0[i], bb[i]);
        float y = fmaxf(gg[i] * (h - mm[i]) * rsqrtf(vv[i] + 1e-5f) + be[i], 0.f);
        o.us[i] = f2bf(y);
    }
    *(uint4*)&hout[(size_t)gid * DD + c] = o.q;
}

// ---------------------------------------------------------------------------
// out = log_softmax( (max_l h_l) @ lin_w + lin_b ). MFMA.
__global__ __launch_bounds__(256) void final_kernel(const ushort* __restrict__ hall,
                                                    size_t hstride, int L,
                                                    const ushort* __restrict__ Wpf,
                                                    const float* __restrict__ lb,
                                                    float* __restrict__ out, int N) {
    __shared__ char slab[4][4096];
    int wave = threadIdx.x >> 6, lane = threadIdx.x & 63;
    int row0 = blockIdx.x * 64 + wave * 16;
    int lrow = lane & 15, kgrp = lane >> 4;
    char* sw = slab[wave];
    size_t tbase = (size_t)row0 * DD;
    int srow = lane >> 4;
    int scolb = (lane & 15) * 16;

#pragma unroll
    for (int i = 0; i < 4; ++i) {
        const ushort* pp = &hall[tbase + i * 512 + lane * 8];
        uint4 m = *(const uint4*)pp;
        for (int l = 1; l < L; ++l)
            m = bfmax4(m, *(const uint4*)(pp + (size_t)l * hstride));
        int row = i * 4 + srow;
        *(uint4*)(sw + swz(row, scolb)) = m;
    }

    BF8 a[4];
#pragma unroll
    for (int kc = 0; kc < 4; ++kc)
        a[kc].q = *(const uint4*)(sw + swz(lrow, kgrp * 16 + kc * 64));

    f32x4 acc[3];
#pragma unroll
    for (int j = 0; j < 3; ++j) acc[j] = (f32x4){0.f, 0.f, 0.f, 0.f};
#pragma unroll
    for (int kc = 0; kc < 4; ++kc) {
#pragma unroll
        for (int j = 0; j < 3; ++j) {
            BF8 b;
            b.q = *(const uint4*)&Wpf[(size_t)((kc * 3 + j) * 64 + lane) * 8];
            acc[j] = __builtin_amdgcn_mfma_f32_16x16x32_bf16(a[kc].v, b.v, acc[j], 0, 0, 0);
        }
    }

    float lbv[3];
#pragma unroll
    for (int j = 0; j < 3; ++j) {
        int col = j * 16 + lrow;
        lbv[j] = (col < CC) ? lb[col] : 0.f;
    }
#pragma unroll
    for (int r = 0; r < 4; ++r) {
        int node = row0 + kgrp * 4 + r;
        float lg[3];
        float m = -1e30f;
#pragma unroll
        for (int j = 0; j < 3; ++j) {
            int col = j * 16 + lrow;
            float v = (col < CC) ? (acc[j][r] + lbv[j]) : -1e30f;
            lg[j] = v;
            m = fmaxf(m, v);
        }
        m = fmaxf(m, __shfl_xor(m, 1));
        m = fmaxf(m, __shfl_xor(m, 2));
        m = fmaxf(m, __shfl_xor(m, 4));
        m = fmaxf(m, __shfl_xor(m, 8));
        float s = 0.f;
#pragma unroll
        for (int j = 0; j < 3; ++j) {
            int col = j * 16 + lrow;
            if (col < CC) s += expf(lg[j] - m);
        }
        s += __shfl_xor(s, 1);
        s += __shfl_xor(s, 2);
        s += __shfl_xor(s, 4);
        s += __shfl_xor(s, 8);
        float lgs = logf(s);
        if (node < N) {
#pragma unroll
            for (int j = 0; j < 3; ++j) {
                int col = j * 16 + lrow;
                if (col < CC) out[(size_t)node * CC + col] = lg[j] - m - lgs;
            }
        }
    }
}

// ---------------------------------------------------------------------------
extern "C" void kernel_launch(void* const* d_in, const int* in_sizes, int n_in,
                              void* d_out, int out_size, void* d_ws, size_t ws_size,
                              hipStream_t stream) {
    const float* x      = (const float*)d_in[0];
    const void*  eidx   = d_in[1];
    const float* conv_w = (const float*)d_in[2];
    const float* conv_b = (const float*)d_in[3];
    const float* gamma  = (const float*)d_in[4];
    const float* beta   = (const float*)d_in[5];
    const float* mean   = (const float*)d_in[6];
    const float* var    = (const float*)d_in[7];
    const float* lin_w  = (const float*)d_in[8];
    const float* lin_b  = (const float*)d_in[9];
    float* out = (float*)d_out;

    const int N = in_sizes[0] / DD;          // 100000
    const int E = in_sizes[1] / 2;           // 800000
    const int L = in_sizes[3] / DD;          // 5
    const int NPAD = (N + 63) & ~63;         // 100032
    const size_t hstride = (size_t)NPAD * DD;
    const int NB = (N + 1023) / 1024;        // scanA blocks
    const int nbk = (N + BSZ - 1) >> BSH;    // buckets (196)
    const int nbb = (E + 4095) / 4096;       // bin blocks

    char* p = (char*)d_ws;
    auto alloc = [&](size_t bytes) -> char* {
        char* r = p;
        p += (bytes + 255) & ~(size_t)255;
        return r;
    };
    ushort* xb     = (ushort*)alloc(hstride * 2);            // mm output hs (per layer)
    ushort* hall   = (ushort*)alloc((size_t)L * hstride * 2);
    ushort* Wf     = (ushort*)alloc((size_t)L * DD * DD * 2);
    ushort* Wpf    = (ushort*)alloc((size_t)12 * 64 * 8 * 2);
    float*  dinv   = (float*)alloc((size_t)N * 4);
    int*    row_ptr= (int*)alloc((size_t)(N + 1) * 4);
    int*    cnt    = (int*)alloc((size_t)N * 4);
    int*    csr    = (int*)alloc((size_t)E * 4);
    unsigned long long* bins = (unsigned long long*)alloc((size_t)E * 8);
    int*    gcursor= (int*)alloc((size_t)nbk * 4);
    int*    blksum = (int*)alloc(128 * 4);
    int*    flag   = (int*)alloc(4);

    detect_kernel<<<1, 64, 0, stream>>>((const unsigned*)eidx, flag);
    hipMemsetAsync(cnt, 0, (size_t)N * 4, stream);
    hist_kernel<<<(E + 255) / 256, 256, 0, stream>>>(eidx, cnt, flag, E);
    scanA_kernel<<<NB, 1024, 0, stream>>>(cnt, row_ptr, dinv, blksum, N);
    scanB_kernel<<<1, 128, 0, stream>>>(blksum, NB);
    scanC_kernel<<<(N + 255) / 256, 256, 0, stream>>>(row_ptr, blksum, N, E);
    initcur_kernel<<<(nbk + 255) / 256, 256, 0, stream>>>(row_ptr, gcursor, nbk);
    bin_kernel<<<nbb, 256, 0, stream>>>(eidx, flag, gcursor, bins, E, nbk);
    bscatter_kernel<<<nbk, 256, 0, stream>>>(bins, row_ptr, csr, N);

    cvtw_kernel<<<(L * 2048 + 255) / 256, 256, 0, stream>>>(conv_w, Wf, L * 2048);
    cvtlw_kernel<<<3, 256, 0, stream>>>(lin_w, Wpf);

    for (int l = 0; l < L; ++l) {
        const ushort* Wl = Wf + (size_t)l * DD * DD;
        if (l == 0)
            mm_kernel<1><<<NPAD / 64, 256, 0, stream>>>(x, Wl, dinv, xb, N);
        else
            mm_kernel<0><<<NPAD / 64, 256, 0, stream>>>(hall + (size_t)(l - 1) * hstride, Wl, dinv, xb, N);
        ushort* hl = hall + (size_t)l * hstride;
        agg_kernel<<<(int)(((size_t)N * 16 + 255) / 256), 256, 0, stream>>>(
            xb, row_ptr, csr, dinv,
            conv_b + (size_t)l * DD, gamma + (size_t)l * DD, beta + (size_t)l * DD,
            mean + (size_t)l * DD, var + (size_t)l * DD, hl, N);
    }
    final_kernel<<<(N + 63) / 64, 256, 0, stream>>>(hall, hstride, L, Wpf, lin_b, out, N);
}